// Round 3
// baseline (2550.706 us; speedup 1.0000x reference)
//
#include <hip/hip_runtime.h>
#include <math.h>

typedef unsigned char u8;

#define KK 16
#define TT 40
#define BB 16
#define NN 32
#define BN 512
#define KBN 8192

// ws float offsets — total 6,317,824 floats = 25,271,296 bytes (~25.3 MB)
#define OFF_FM   0u          // B*80*80*32 = 3276800   fm (b,oh,ow,oc)
#define OFF_C1   3276800u    // B*16*80*80 = 1638400
#define OFF_W2T  4915200u    // 12800  conv2 W as (ic,kh,kw,oc)
#define OFF_WG   4928000u    // 48*1728 = 82944  wg[hh][o*48+cc] = scf_w[cc][o*48+hh]
#define OFF_WT   5010944u    // 144*144 = 20736  wt[kk][o] = [Wih|Whh][o][kk]
#define OFF_G    5031680u    // 512*1728 = 884736
#define OFF_H    5916416u    // 8192*48 = 393216
#define OFF_SC   6309632u    // 8192

__global__ __launch_bounds__(256) void k_init(const float* hx, float* h, float* score){
  int idx = blockIdx.x*256 + threadIdx.x;
  if (idx < KBN*48) h[idx] = hx[idx % (BN*48)];
  if (idx < KBN) score[idx] = 0.f;
}

__global__ __launch_bounds__(256) void k_prep(const float* conv2_w, const float* scfw,
                                              const float* wih, const float* whh,
                                              float* w2t, float* wg, float* wt){
  int idx = blockIdx.x*256 + threadIdx.x;
  if (idx < 12800) {
    int oc = idx & 31; int rest = idx >> 5;        // rest = ic*25+kh*5+kw
    w2t[idx] = conv2_w[oc*400 + rest];
  }
  int i2 = idx - 12800;
  if (i2 >= 0 && i2 < 48*1728) {
    int hh = i2 / 1728, col = i2 % 1728;
    int o = col / 48, cc = col % 48;
    wg[i2] = scfw[cc*1728 + o*48 + hh];
  }
  int i3 = idx - (12800 + 48*1728);
  if (i3 >= 0 && i3 < 144*144) {
    int kk2 = i3 % 144, o = i3 / 144;
    float v = (kk2 < 96) ? wih[o*96 + kk2] : whh[o*48 + (kk2 - 96)];
    wt[kk2*144 + o] = v;
  }
}

__global__ __launch_bounds__(256) void k_conv1(const float* img, const float* w1, const float* b1, float* c1){
  int idx = blockIdx.x*256 + threadIdx.x;          // (b,oc,oh,ow) ow fastest
  int ow = idx % 80, t1 = idx / 80;
  int oh = t1 % 80, t2 = t1 / 80;
  int oc = t2 % 16, b = t2 / 16;
  float acc = b1[oc];
  for (int ic = 0; ic < 4; ++ic)
    for (int kh = 0; kh < 5; ++kh) {
      int ih = oh*2 - 2 + kh;
      if (ih < 0 || ih >= 160) continue;
      const float* ip = img + ((b*4 + ic)*160 + ih)*160;
      const float* wp = w1 + ((oc*4 + ic)*5 + kh)*5;
      #pragma unroll
      for (int kw = 0; kw < 5; ++kw) {
        int iw = ow*2 - 2 + kw;
        if (iw >= 0 && iw < 160) acc += ip[iw] * wp[kw];
      }
    }
  c1[idx] = fmaxf(acc, 0.f);
}

__global__ __launch_bounds__(256) void k_conv2(const float* c1, const float* w2t, const float* b2, float* fm){
  int idx = blockIdx.x*256 + threadIdx.x;          // (b,oh,owg,oc) oc fastest, 4 ow per thread
  int oc = idx & 31;
  int t1 = idx >> 5;
  int owg = t1 % 20; int t2 = t1 / 20;
  int oh = t2 % 80; int b = t2 / 80;
  int ow0 = owg*4;
  float acc0=b2[oc],acc1=b2[oc],acc2=b2[oc],acc3=b2[oc];
  for (int ic = 0; ic < 16; ++ic)
    for (int kh = 0; kh < 5; ++kh) {
      int ih = oh - 2 + kh;
      if (ih < 0 || ih >= 80) continue;
      const float* ip = c1 + ((b*16 + ic)*80 + ih)*80;
      float cv[8];
      #pragma unroll
      for (int q = 0; q < 8; ++q) {
        int iw = ow0 - 2 + q;
        cv[q] = (iw >= 0 && iw < 80) ? ip[iw] : 0.f;
      }
      const float* wp = w2t + (ic*25 + kh*5)*32 + oc;
      #pragma unroll
      for (int kw = 0; kw < 5; ++kw) {
        float wv = wp[kw*32];
        acc0 += cv[kw]   * wv;
        acc1 += cv[kw+1] * wv;
        acc2 += cv[kw+2] * wv;
        acc3 += cv[kw+3] * wv;
      }
    }
  float* op = fm + ((b*80 + oh)*80 + ow0)*32 + oc;
  op[0]  = fmaxf(acc0, 0.f);
  op[32] = fmaxf(acc1, 0.f);
  op[64] = fmaxf(acc2, 0.f);
  op[96] = fmaxf(acc3, 0.f);
}

__global__ __launch_bounds__(256) void k_g(const float* h, const float* wg, float* G){
  int cb = blockIdx.x % 7, rg = blockIdx.x / 7;   // 7 col blocks x 64 row groups(8)
  int col = cb*256 + threadIdx.x;
  int r0 = rg*8;
  __shared__ float hs[8][49];
  for (int i = threadIdx.x; i < 8*48; i += 256) hs[i/48][i%48] = h[(r0 + i/48)*48 + (i%48)];
  __syncthreads();
  if (col >= 1728) return;
  float acc[8] = {0,0,0,0,0,0,0,0};
  for (int kk2 = 0; kk2 < 48; ++kk2) {
    float wv = wg[kk2*1728 + col];
    #pragma unroll
    for (int r = 0; r < 8; ++r) acc[r] += hs[r][kk2] * wv;
  }
  #pragma unroll
  for (int r = 0; r < 8; ++r) G[(r0 + r)*1728 + col] = acc[r];
}

__global__ __launch_bounds__(256) void k_step(
    const float* y_path, const float* cur_loc, const float* fm,
    const float* G,
    const float* vw, const float* vb2, const float* scfb,
    const float* wt, const float* bih, const float* bhh,
    const float* scw, const float* scb,
    float* h, float* score, int t)
{
  __shared__ float X[32][149];    // [r][0..95]=x, [96..143]=h
  __shared__ float GS[32][145];   // gi+gh (144)
  __shared__ float GH[32][49];    // gh[96:144]
  __shared__ float PX[32], PY[32];
  __shared__ float WJQ[32][33];
  __shared__ u8 BINM[32][32];
  int tid = threadIdx.x;
  int row0 = blockIdx.x * 32;     // 32 | 512 -> whole block shares k and b
  int kk = row0 >> 9;
  int bb = (row0 >> 5) & 15;

  // stage 0a: agent positions for this (k,b,t)
  if (tid < 32) {
    PX[tid] = y_path[((kk*TT + t)*BN + bb*32 + tid)*2];
    PY[tid] = y_path[((kk*TT + t)*BN + bb*32 + tid)*2 + 1];
  }
  __syncthreads();

  // stage 0b: 32x32 pair bins (c = other(q) - agent(j))
  for (int it = 0; it < 4; ++it) {
    int p = tid + it*256;
    int j = p >> 5, q = p & 31;
    float dx = PX[q] - PX[j], dy = PY[q] - PY[j];
    float dist = sqrtf(dx*dx + dy*dy);
    int bin = 255;
    if (q != j && dist >= 0.5f && dist <= 4.0f) {
      float ct = fminf(1.f, fmaxf(-1.f, dx / dist));
      float costh = acosf(ct);
      float theta = (dy < -0.01f) ? (6.28318530717958647692f - costh) : costh;
      int ub = (int)((dist - 0.5f) / 0.58333331346511840820f);
      ub = min(max(ub, 0), 5);
      int vb = (int)(theta / 1.04719758033752441406f);
      vb = min(max(vb, 0), 5);
      bin = ub*6 + vb;
    }
    BINM[j][q] = (u8)bin;
  }
  __syncthreads();

  // stage 0c: weights 1/cnt per (j, bin)
  for (int it = 0; it < 4; ++it) {
    int p = tid + it*256;
    int j = p >> 5, q = p & 31;
    int bq = BINM[j][q];
    float w = 0.f;
    if (bq != 255) {
      int cnt = 0;
      #pragma unroll
      for (int q2 = 0; q2 < 32; ++q2) cnt += (BINM[j][q2] == bq) ? 1 : 0;
      w = 1.0f / (float)cnt;
    }
    WJQ[j][q] = w;
  }
  __syncthreads();

  // stage 1: assemble X
  for (int it = 0; it < 18; ++it) {
    int task = tid + it*256;                      // 32*144
    int r = task / 144, c = task % 144;
    int row = row0 + r;
    int rr = row & 511;
    int j = rr & 31;
    float val;
    if (c < 32) {
      int u = min(max(40 - (int)PY[j], 0), 79);
      int v = min(max((int)PX[j], 0), 79);
      val = fm[((bb*80 + u)*80 + v)*32 + c];
    } else if (c < 48) {
      int o = c - 32;
      float qx, qy;
      if (t == 0) { qx = cur_loc[rr*2]; qy = cur_loc[rr*2 + 1]; }
      else { qx = y_path[((kk*TT + t - 1)*BN + rr)*2]; qy = y_path[((kk*TT + t - 1)*BN + rr)*2 + 1]; }
      float vx = (PX[j] - qx)*10.f, vy = (PY[j] - qy)*10.f;
      val = vx*vw[o*2] + vy*vw[o*2 + 1] + vb2[o];
    } else if (c < 96) {
      int o = c - 48;
      float acc = scfb[o];
      for (int q = 0; q < 32; ++q) {
        int bin = BINM[j][q];
        if (bin != 255) acc += WJQ[j][q] * G[(bb*32 + q)*1728 + bin*48 + o];
      }
      val = acc;
    } else {
      val = h[row*48 + (c - 96)];
    }
    X[r][c] = val;
  }
  __syncthreads();

  // stage 2: gsum = x@Wih^T + h@Whh^T (+both biases), plus gh3 = h@Whh[96:]^T + bhh[96:]
  int tx = tid & 15, ty = tid >> 4;
  int r0 = ty*2;
  float acc[2][9];
  #pragma unroll
  for (int ri = 0; ri < 2; ++ri)
    #pragma unroll
    for (int jj = 0; jj < 9; ++jj) acc[ri][jj] = 0.f;
  for (int kk2 = 0; kk2 < 144; ++kk2) {
    float x0 = X[r0][kk2], x1 = X[r0 + 1][kk2];
    #pragma unroll
    for (int jj = 0; jj < 9; ++jj) {
      float wv = wt[kk2*144 + tx + 16*jj];
      acc[0][jj] += x0*wv;
      acc[1][jj] += x1*wv;
    }
  }
  #pragma unroll
  for (int ri = 0; ri < 2; ++ri)
    #pragma unroll
    for (int jj = 0; jj < 9; ++jj) {
      int o = tx + 16*jj;
      GS[r0 + ri][o] = acc[ri][jj] + bih[o] + bhh[o];
    }
  float a2[2][3] = {{0,0,0},{0,0,0}};
  for (int kk2 = 0; kk2 < 48; ++kk2) {
    float x0 = X[r0][96 + kk2], x1 = X[r0 + 1][96 + kk2];
    #pragma unroll
    for (int jj = 0; jj < 3; ++jj) {
      float wv = wt[(96 + kk2)*144 + 96 + tx + 16*jj];
      a2[0][jj] += x0*wv;
      a2[1][jj] += x1*wv;
    }
  }
  #pragma unroll
  for (int ri = 0; ri < 2; ++ri)
    #pragma unroll
    for (int jj = 0; jj < 3; ++jj) {
      int o = tx + 16*jj;
      GH[r0 + ri][o] = a2[ri][jj] + bhh[96 + o];
    }
  __syncthreads();

  // stage 3: GRU update   nn = tanh(gsum3 + (r-1)*gh3)
  for (int it = 0; it < 6; ++it) {
    int task = tid + it*256;                      // 32*48
    int r = task / 48, c = task % 48;
    float g0 = GS[r][c], g1 = GS[r][48 + c], g3 = GS[r][96 + c];
    float gh = GH[r][c];
    float hold = X[r][96 + c];
    float rg = 1.f/(1.f + expf(-g0));
    float zg = 1.f/(1.f + expf(-g1));
    float nn2 = tanhf(g3 + (rg - 1.f)*gh);
    float hn = (1.f - zg)*nn2 + zg*hold;
    h[(row0 + r)*48 + c] = hn;
    X[r][96 + c] = hn;
  }
  __syncthreads();

  // stage 4: score accumulation
  if (tid < 32) {
    float s = scb[0];
    #pragma unroll
    for (int c = 0; c < 48; ++c) s += X[tid][96 + c]*scw[c];
    score[row0 + tid] += s;
  }
}

__global__ __launch_bounds__(256) void k_out(const float* h, const float* score,
                                             const float* dyw, const float* dyb, float* out)
{
  int idx = blockIdx.x*256 + threadIdx.x;
  if (idx < KBN*80) {
    int row = idx / 80, c = idx % 80;
    float acc = dyb[c];
    const float* hp = h + row*48;
    const float* wp = dyw + c*48;
    #pragma unroll
    for (int i = 0; i < 48; ++i) acc += hp[i]*wp[i];
    int k = row >> 9, rr = row & 511;
    int d = c / 40, tq = c % 40;
    out[((k*40 + tq)*512 + rr)*2 + d] = acc;
  } else {
    int r2 = idx - KBN*80;
    if (r2 < KBN) out[KBN*80 + r2] = score[r2];
  }
}

extern "C" void kernel_launch(void* const* d_in, const int* in_sizes, int n_in,
                              void* d_out, int out_size, void* d_ws, size_t ws_size,
                              hipStream_t stream)
{
  const float* hx   = (const float*)d_in[0];
  const float* cl   = (const float*)d_in[1];
  const float* yp   = (const float*)d_in[2];
  const float* img  = (const float*)d_in[3];
  const float* w1   = (const float*)d_in[4];
  const float* b1   = (const float*)d_in[5];
  const float* w2   = (const float*)d_in[6];
  const float* b2   = (const float*)d_in[7];
  const float* vw   = (const float*)d_in[8];
  const float* vb   = (const float*)d_in[9];
  const float* scfw = (const float*)d_in[10];
  const float* scfb = (const float*)d_in[11];
  const float* wih  = (const float*)d_in[12];
  const float* whh  = (const float*)d_in[13];
  const float* bih  = (const float*)d_in[14];
  const float* bhh  = (const float*)d_in[15];
  const float* dyw  = (const float*)d_in[16];
  const float* dyb  = (const float*)d_in[17];
  const float* scw  = (const float*)d_in[18];
  const float* scb  = (const float*)d_in[19];

  float* ws  = (float*)d_ws;
  float* fm  = ws + OFF_FM;
  float* c1  = ws + OFF_C1;
  float* w2t = ws + OFF_W2T;
  float* wg  = ws + OFF_WG;
  float* wt  = ws + OFF_WT;
  float* G   = ws + OFF_G;
  float* h   = ws + OFF_H;
  float* sc  = ws + OFF_SC;
  float* out = (float*)d_out;

  hipLaunchKernelGGL(k_init,  dim3(1536), dim3(256), 0, stream, hx, h, sc);
  hipLaunchKernelGGL(k_prep,  dim3(455),  dim3(256), 0, stream, w2, scfw, wih, whh, w2t, wg, wt);
  hipLaunchKernelGGL(k_conv1, dim3(6400), dim3(256), 0, stream, img, w1, b1, c1);
  hipLaunchKernelGGL(k_conv2, dim3(3200), dim3(256), 0, stream, c1, w2t, b2, fm);
  for (int t = 0; t < TT; ++t) {
    hipLaunchKernelGGL(k_g,    dim3(448), dim3(256), 0, stream, h, wg, G);
    hipLaunchKernelGGL(k_step, dim3(256), dim3(256), 0, stream,
        yp, cl, fm, G, vw, vb, scfb, wt, bih, bhh, scw, scb, h, sc, t);
  }
  hipLaunchKernelGGL(k_out, dim3(2592), dim3(256), 0, stream, h, sc, dyw, dyb, out);
}

// Round 5
// 1761.026 us; speedup vs baseline: 1.4484x; 1.4484x over previous
//
#include <hip/hip_runtime.h>
#include <math.h>

typedef unsigned char u8;

#define KK 16
#define TT 40
#define BB 16
#define NN 32
#define BN 512
#define KBN 8192

// ws float offsets — total 5,828,608 floats = 23,314,432 bytes (~23.3 MB)
#define OFF_FM   0u          // 16*80*80*32 = 3276800   fm (b,oh,ow,oc)
#define OFF_C1   3276800u    // 16*16*80*80 = 1638400
#define OFF_W2T  4915200u    // 12800   conv2 W as (ic,kh,kw,oc)
#define OFF_WT9  4928000u    // 20736   wt9[kk2][c][g] g in {r,z,n}: gate-aligned GRU weights
#define OFF_WH3  4948736u    // 2304    wh3[kk2s][c] = whh[(96+c)*48+kk2s]  (n-gate h weights)
#define OFF_WGT  4951040u    // 82944   wgt[bin][hh][cc] = scfw[cc][bin*48+hh]
#define OFF_H0   5033984u    // 8192*48 = 393216  (h ping)
#define OFF_H1   5427200u    // 8192*48 = 393216  (h pong)
#define OFF_SC   5820416u    // 8192

__global__ __launch_bounds__(256) void k_init(const float* hx, float* h, float* score){
  int idx = blockIdx.x*256 + threadIdx.x;
  if (idx < KBN*48) h[idx] = hx[idx % (BN*48)];
  if (idx < KBN) score[idx] = 0.f;
}

__global__ __launch_bounds__(256) void k_prep(const float* conv2_w, const float* scfw,
                                              const float* wih, const float* whh,
                                              float* w2t, float* wt9g, float* wh3g, float* wgt_g){
  int idx = blockIdx.x*256 + threadIdx.x;
  if (idx < 12800) {
    int oc = idx & 31; int rest = idx >> 5;        // rest = ic*25+kh*5+kw
    w2t[idx] = conv2_w[oc*400 + rest];
  }
  int i2 = idx - 12800;
  if (i2 >= 0 && i2 < 20736) {                     // wt9[kk2][c][g], o = g*48+c
    int kk2 = i2 / 144, rem = i2 % 144;
    int c = rem / 3, g = rem % 3;
    int o = g*48 + c;
    wt9g[i2] = (kk2 < 96) ? wih[o*96 + kk2] : whh[o*48 + (kk2 - 96)];
  }
  int i3 = idx - 33536;
  if (i3 >= 0 && i3 < 2304) {                      // wh3[kk2s][c]
    int kk2s = i3 / 48, c = i3 % 48;
    wh3g[i3] = whh[(96 + c)*48 + kk2s];
  }
  int i4 = idx - 35840;
  if (i4 >= 0 && i4 < 82944) {                     // wgt[bin][hh][cc]
    int bin = i4 / 2304, r2 = i4 % 2304;
    int hh = r2 / 48, cc = r2 % 48;
    wgt_g[i4] = scfw[cc*1728 + bin*48 + hh];
  }
}

__global__ __launch_bounds__(256) void k_conv1(const float* img, const float* w1, const float* b1, float* c1){
  int idx = blockIdx.x*256 + threadIdx.x;          // (b,oc,oh,ow) ow fastest
  int ow = idx % 80, t1 = idx / 80;
  int oh = t1 % 80, t2 = t1 / 80;
  int oc = t2 % 16, b = t2 / 16;
  float acc = b1[oc];
  for (int ic = 0; ic < 4; ++ic)
    for (int kh = 0; kh < 5; ++kh) {
      int ih = oh*2 - 2 + kh;
      if (ih < 0 || ih >= 160) continue;
      const float* ip = img + ((b*4 + ic)*160 + ih)*160;
      const float* wp = w1 + ((oc*4 + ic)*5 + kh)*5;
      #pragma unroll
      for (int kw = 0; kw < 5; ++kw) {
        int iw = ow*2 - 2 + kw;
        if (iw >= 0 && iw < 160) acc += ip[iw] * wp[kw];
      }
    }
  c1[idx] = fmaxf(acc, 0.f);
}

__global__ __launch_bounds__(256) void k_conv2(const float* c1, const float* w2t, const float* b2, float* fm){
  int idx = blockIdx.x*256 + threadIdx.x;          // (b,oh,owg,oc) oc fastest, 4 ow per thread
  int oc = idx & 31;
  int t1 = idx >> 5;
  int owg = t1 % 20; int t2 = t1 / 20;
  int oh = t2 % 80; int b = t2 / 80;
  int ow0 = owg*4;
  float acc0=b2[oc],acc1=b2[oc],acc2=b2[oc],acc3=b2[oc];
  for (int ic = 0; ic < 16; ++ic)
    for (int kh = 0; kh < 5; ++kh) {
      int ih = oh - 2 + kh;
      if (ih < 0 || ih >= 80) continue;
      const float* ip = c1 + ((b*16 + ic)*80 + ih)*80;
      float cv[8];
      #pragma unroll
      for (int q = 0; q < 8; ++q) {
        int iw = ow0 - 2 + q;
        cv[q] = (iw >= 0 && iw < 80) ? ip[iw] : 0.f;
      }
      const float* wp = w2t + (ic*25 + kh*5)*32 + oc;
      #pragma unroll
      for (int kw = 0; kw < 5; ++kw) {
        float wv = wp[kw*32];
        acc0 += cv[kw]   * wv;
        acc1 += cv[kw+1] * wv;
        acc2 += cv[kw+2] * wv;
        acc3 += cv[kw+3] * wv;
      }
    }
  float* op = fm + ((b*80 + oh)*80 + ow0)*32 + oc;
  op[0]  = fmaxf(acc0, 0.f);
  op[32] = fmaxf(acc1, 0.f);
  op[64] = fmaxf(acc2, 0.f);
  op[96] = fmaxf(acc3, 0.f);
}

// One launch per timestep. Block = one (k,b) panel of 32 agents.
// h is double-buffered across launches: read hin only, write hout only (race-free).
__global__ __launch_bounds__(256) void k_step2(
    const float* __restrict__ y_path, const float* __restrict__ cur_loc,
    const float* __restrict__ fm, const float* __restrict__ wgt,
    const float* __restrict__ wt9g,
    const float* __restrict__ vw, const float* __restrict__ vb2,
    const float* __restrict__ scfb, const float* __restrict__ bih,
    const float* __restrict__ bhh, const float* __restrict__ scw,
    const float* __restrict__ scb, const float* __restrict__ dyw,
    const float* __restrict__ dyb,
    const float* __restrict__ hin, float* __restrict__ hout,
    float* __restrict__ score, float* __restrict__ out, int t)
{
  __align__(16) __shared__ float wts[23040];   // [0,20736) wt9, [20736,23040) wh3
  __shared__ float X[32][148];                 // [0..95]=x, [96..143]=h(old)
  __shared__ float HnL[32][49];                // k=0 hidden panel for this b (from hin)
  __shared__ float PXs[32], PYs[32];
  __shared__ u8 BINM[32][32];
  __shared__ int PLE[1024];                    // (bin<<16)|(j<<8)|q
  __shared__ float PWL[1024];
  __shared__ float SROW[32];
  __shared__ int lcnt;

  int tid = threadIdx.x;
  int row0 = blockIdx.x * 32;
  int kk = blockIdx.x >> 4;
  int bb = blockIdx.x & 15;

  // ---- phase A: stage weights (float4) + hidden + positions
  {
    const float4* src = reinterpret_cast<const float4*>(wt9g);  // wt9g & wh3g contiguous in ws
    float4* dst = reinterpret_cast<float4*>(wts);
    for (int i = tid; i < 5760; i += 256) dst[i] = src[i];
  }
  for (int i = tid; i < 1536; i += 256) { int r = i/48, c = i%48; X[r][96+c] = hin[(row0+r)*48 + c]; }
  for (int i = tid; i < 1536; i += 256) { int r = i/48, c = i%48; HnL[r][c] = hin[(bb*32+r)*48 + c]; }
  if (tid < 32) {
    PXs[tid] = y_path[((kk*TT + t)*BN + bb*32 + tid)*2];
    PYs[tid] = y_path[((kk*TT + t)*BN + bb*32 + tid)*2 + 1];
    SROW[tid] = 0.f;
  }
  if (tid == 0) lcnt = 0;
  __syncthreads();

  // ---- phase B: 32x32 pair bins (c = other(q) - agent(j))
  for (int it2 = 0; it2 < 4; ++it2) {
    int p = tid + it2*256;
    int j = p >> 5, q = p & 31;
    float dx = PXs[q] - PXs[j], dy = PYs[q] - PYs[j];
    float dist = sqrtf(dx*dx + dy*dy);
    int bin = 255;
    if (q != j && dist >= 0.5f && dist <= 4.0f) {
      float ct = fminf(1.f, fmaxf(-1.f, dx / dist));
      float costh = acosf(ct);
      float theta = (dy < -0.01f) ? (6.28318530717958647692f - costh) : costh;
      int ub = (int)((dist - 0.5f) / 0.58333331346511840820f);
      ub = min(max(ub, 0), 5);
      int vb = (int)(theta / 1.04719758033752441406f);
      vb = min(max(vb, 0), 5);
      bin = ub*6 + vb;
    }
    BINM[j][q] = (u8)bin;
  }
  __syncthreads();

  // ---- phase C: compact pair list (w = 1/cnt) + x-assembly (feat | vel | scfb-init)
  for (int it2 = 0; it2 < 4; ++it2) {
    int p = tid + it2*256;
    int j = p >> 5, q = p & 31;
    int bq = BINM[j][q];
    if (bq != 255) {
      int cnt2 = 0;
      #pragma unroll
      for (int q2 = 0; q2 < 32; ++q2) cnt2 += (BINM[j][q2] == bq) ? 1 : 0;
      int idx2 = atomicAdd(&lcnt, 1);
      PLE[idx2] = (bq << 16) | (j << 8) | q;
      PWL[idx2] = 1.0f / (float)cnt2;
    }
  }
  for (int it2 = 0; it2 < 12; ++it2) {
    int task = tid + it2*256;            // 32*96
    int r = task / 96, c = task % 96;
    int rr = (row0 + r) & 511;
    float val;
    if (c < 32) {
      int u = min(max(40 - (int)PYs[r], 0), 79);
      int v = min(max((int)PXs[r], 0), 79);
      val = fm[((bb*80 + u)*80 + v)*32 + c];
    } else if (c < 48) {
      int o = c - 32;
      float qx, qy;
      if (t == 0) { qx = cur_loc[rr*2]; qy = cur_loc[rr*2 + 1]; }
      else { qx = y_path[((kk*TT + t - 1)*BN + rr)*2]; qy = y_path[((kk*TT + t - 1)*BN + rr)*2 + 1]; }
      float vx = (PXs[r] - qx)*10.f, vy = (PYs[r] - qy)*10.f;
      val = vx*vw[o*2] + vy*vw[o*2 + 1] + vb2[o];
    } else {
      val = scfb[c - 48];
    }
    X[r][c] = val;
  }
  __syncthreads();

  // ---- phase D: sparse social pooling  rhalf[j] += w * (HnL[q] @ Wblock[bin])
  int P = lcnt;
  {
    int wid = tid >> 6, lane = tid & 63;
    if (lane < 48) {
      for (int p = wid; p < P; p += 4) {
        int e = PLE[p];
        int bin = e >> 16, j = (e >> 8) & 31, q = e & 31;
        float wv = PWL[p];
        const float* wp = wgt + bin*2304 + lane;
        float acc = 0.f;
        #pragma unroll
        for (int hh = 0; hh < 48; ++hh) acc += HnL[q][hh] * wp[hh*48];
        atomicAdd(&X[j][48 + lane], wv * acc);
      }
    }
  }
  __syncthreads();

  // ---- phase E: GRU GEMM in registers (thread owns cols {3tx,3tx+1,3tx+2}, all gates)
  const float* wt9 = wts;
  const float* wh3 = wts + 20736;
  int tx = tid & 15, ty = tid >> 4;
  int r0 = ty*2;
  float a9[2][9], a3[2][3];
  #pragma unroll
  for (int ri = 0; ri < 2; ++ri) {
    #pragma unroll
    for (int m = 0; m < 9; ++m) a9[ri][m] = 0.f;
    #pragma unroll
    for (int m = 0; m < 3; ++m) a3[ri][m] = 0.f;
  }
  for (int k2 = 0; k2 < 144; ++k2) {
    float x0 = X[r0][k2], x1 = X[r0+1][k2];
    const float* wr = wt9 + k2*144 + 9*tx;
    #pragma unroll
    for (int m = 0; m < 9; ++m) {
      float wvm = wr[m];
      a9[0][m] += x0*wvm;
      a9[1][m] += x1*wvm;
    }
  }
  for (int k2 = 0; k2 < 48; ++k2) {
    float x0 = X[r0][96+k2], x1 = X[r0+1][96+k2];
    const float* wr = wh3 + k2*48 + 3*tx;
    #pragma unroll
    for (int m = 0; m < 3; ++m) {
      float wvm = wr[m];
      a3[0][m] += x0*wvm;
      a3[1][m] += x1*wvm;
    }
  }
  float hn[2][3];
  #pragma unroll
  for (int ri = 0; ri < 2; ++ri)
    #pragma unroll
    for (int c3 = 0; c3 < 3; ++c3) {
      int c = 3*tx + c3;
      float gR = a9[ri][3*c3+0] + bih[c]    + bhh[c];
      float gZ = a9[ri][3*c3+1] + bih[48+c] + bhh[48+c];
      float gN = a9[ri][3*c3+2] + bih[96+c] + bhh[96+c];
      float g3 = a3[ri][c3] + bhh[96+c];
      float rg = 1.f/(1.f + expf(-gR));
      float zg = 1.f/(1.f + expf(-gZ));
      float nn2 = tanhf(gN + (rg - 1.f)*g3);
      float hold = X[r0+ri][96+c];
      hn[ri][c3] = (1.f - zg)*nn2 + zg*hold;
    }
  __syncthreads();   // all reads of old h (X, HnL) complete before X is overwritten

  // ---- phase F: commit h (LDS + hout) + score partials
  float sp0 = 0.f, sp1 = 0.f;
  #pragma unroll
  for (int c3 = 0; c3 < 3; ++c3) {
    int c = 3*tx + c3;
    X[r0][96+c]   = hn[0][c3];
    X[r0+1][96+c] = hn[1][c3];
    hout[(row0+r0)*48 + c]   = hn[0][c3];
    hout[(row0+r0+1)*48 + c] = hn[1][c3];
    sp0 += hn[0][c3]*scw[c];
    sp1 += hn[1][c3]*scw[c];
  }
  atomicAdd(&SROW[r0], sp0);
  atomicAdd(&SROW[r0+1], sp1);
  __syncthreads();

  // ---- phase G: score update (+ final outputs at t = T-1)
  if (tid < 32) {
    float s = score[row0 + tid] + SROW[tid] + scb[0];
    score[row0 + tid] = s;
    if (t == TT-1) out[KBN*80 + row0 + tid] = s;
  }
  if (t == TT-1) {
    for (int it2 = 0; it2 < 10; ++it2) {
      int task = tid + it2*256;          // 32*80
      int r = task / 80, c = task % 80;
      float acc = dyb[c];
      #pragma unroll
      for (int i = 0; i < 48; ++i) acc += X[r][96+i] * dyw[c*48 + i];
      int rr = (row0 + r) & 511;
      int d = c / 40, tq = c % 40;
      out[((kk*40 + tq)*512 + rr)*2 + d] = acc;
    }
  }
}

extern "C" void kernel_launch(void* const* d_in, const int* in_sizes, int n_in,
                              void* d_out, int out_size, void* d_ws, size_t ws_size,
                              hipStream_t stream)
{
  const float* hx   = (const float*)d_in[0];
  const float* cl   = (const float*)d_in[1];
  const float* yp   = (const float*)d_in[2];
  const float* img  = (const float*)d_in[3];
  const float* w1   = (const float*)d_in[4];
  const float* b1   = (const float*)d_in[5];
  const float* w2   = (const float*)d_in[6];
  const float* b2   = (const float*)d_in[7];
  const float* vw   = (const float*)d_in[8];
  const float* vb   = (const float*)d_in[9];
  const float* scfw = (const float*)d_in[10];
  const float* scfb = (const float*)d_in[11];
  const float* wih  = (const float*)d_in[12];
  const float* whh  = (const float*)d_in[13];
  const float* bih  = (const float*)d_in[14];
  const float* bhh  = (const float*)d_in[15];
  const float* dyw  = (const float*)d_in[16];
  const float* dyb  = (const float*)d_in[17];
  const float* scw  = (const float*)d_in[18];
  const float* scb  = (const float*)d_in[19];

  float* ws   = (float*)d_ws;
  float* fm   = ws + OFF_FM;
  float* c1   = ws + OFF_C1;
  float* w2t  = ws + OFF_W2T;
  float* wt9g = ws + OFF_WT9;
  float* wh3g = ws + OFF_WH3;
  float* wgtg = ws + OFF_WGT;
  float* hb0  = ws + OFF_H0;
  float* hb1  = ws + OFF_H1;
  float* sc   = ws + OFF_SC;
  float* out  = (float*)d_out;

  hipLaunchKernelGGL(k_init,  dim3(1536), dim3(256), 0, stream, hx, hb0, sc);
  hipLaunchKernelGGL(k_prep,  dim3(464),  dim3(256), 0, stream, w2, scfw, wih, whh, w2t, wt9g, wh3g, wgtg);
  hipLaunchKernelGGL(k_conv1, dim3(6400), dim3(256), 0, stream, img, w1, b1, c1);
  hipLaunchKernelGGL(k_conv2, dim3(3200), dim3(256), 0, stream, c1, w2t, b2, fm);
  for (int t = 0; t < TT; ++t) {
    float* hin  = (t & 1) ? hb1 : hb0;
    float* hout = (t & 1) ? hb0 : hb1;
    hipLaunchKernelGGL(k_step2, dim3(256), dim3(256), 0, stream,
        yp, cl, fm, wgtg, wt9g, vw, vb, scfb, bih, bhh, scw, scb, dyw, dyb, hin, hout, sc, out, t);
  }
}